// Round 4
// baseline (144.861 us; speedup 1.0000x reference)
//
#include <hip/hip_runtime.h>

typedef __bf16 bf16x8 __attribute__((ext_vector_type(8)));
typedef float f32x4 __attribute__((ext_vector_type(4)));
typedef unsigned short u16;
typedef unsigned short u16x4 __attribute__((ext_vector_type(4)));
typedef unsigned short u16x8 __attribute__((ext_vector_type(8)));

#define MFMA16(a, b, c) __builtin_amdgcn_mfma_f32_16x16x32_bf16(a, b, c, 0, 0, 0)

__device__ __forceinline__ u16 f2bf(float f) {
    unsigned u = __builtin_bit_cast(unsigned, f);
    u += 0x7fffu + ((u >> 16) & 1u);   // RNE
    return (u16)(u >> 16);
}

__device__ __forceinline__ bf16x8 ld_frag(const u16* p) {
    u16x8 v = *(const u16x8*)p;
    return __builtin_bit_cast(bf16x8, v);
}

__device__ __forceinline__ u16x8 pack8(float4 a, float4 b) {
    u16x8 o = { f2bf(a.x), f2bf(a.y), f2bf(a.z), f2bf(a.w),
                f2bf(b.x), f2bf(b.y), f2bf(b.z), f2bf(b.w) };
    return o;
}

__device__ __forceinline__ u16x4 pack4(float4 a) {
    u16x4 o = { f2bf(a.x), f2bf(a.y), f2bf(a.z), f2bf(a.w) };
    return o;
}

// Raw barrier: drains LDS ops only (ds_write visibility), does NOT drain
// vmcnt — register-destination global loads stay in flight across it.
// sched_barrier(0) after the asm: rule-#18 hardening.
__device__ __forceinline__ void wg_barrier() {
    asm volatile("s_waitcnt lgkmcnt(0)" ::: "memory");
    __builtin_amdgcn_sched_barrier(0);
    __builtin_amdgcn_s_barrier();
}

// ---------------------------------------------------------------------------
// wcvt: Wq|Wk|Wv fp32 -> Wb bf16, N-fused B-fragment order, BK=32 chunks.
// Wb u16 off = ((cc*24 + n16)*64 + lane)*8 ;  lane=(quad,l16), cc in 0..31
// element = Wcat[n16*16 + l16][cc*32 + quad*8 + j],  Wcat=[Wq;Wk;Wv]
// ---------------------------------------------------------------------------
__global__ __launch_bounds__(256) void wcvt(
    const float* __restrict__ Wq, const float* __restrict__ Wk,
    const float* __restrict__ Wv, u16* __restrict__ Wb)
{
    int g = blockIdx.x * 256 + threadIdx.x;   // 49152
    int lane = g & 63, l16 = g & 15, quad = (g >> 4) & 3;
    int n16 = (g >> 6) % 24;
    int cc  = (g >> 6) / 24;
    int nrow = n16 * 16 + l16;                // 0..383
    int nt = nrow >> 7, r = nrow & 127;
    int col = cc * 32 + quad * 8;
    const float* W = (nt == 0 ? Wq : nt == 1 ? Wk : Wv) + (size_t)r * 1024 + col;
    float4 a = *(const float4*)(W);
    float4 b = *(const float4*)(W + 4);
    (void)lane;
    *(u16x8*)(Wb + (size_t)g * 8) = pack8(a, b);
}

// ---------------------------------------------------------------------------
// qkv_fused v4: q|k|v = x @ W^T + b.  grid 512 (M-tile 32), 512 thr / 8 waves.
// N=384 fully fused (x read ONCE). BK=32.
// Change vs v3 (v3 post-mortem): VGPR_Count=52 proved the compiler SANK the
// distance-2/4 prefetch loads to their use sites (the pipeline never existed
// in the binary; 76+ VGPR of declared pipeline state can't fit in 52).
// Fix: per-iteration issue cluster [x(c+4), B(c+2)] closed by
// sched_barrier(0) — loads must be issued there, registers stay live,
// waits at use become counted-vmcnt on in-flight data.
// Verification signal: VGPR_Count should jump to ~90-110.
// Wave tile 32m x 48n: 2 A-frags, 3 B-frags, 6 MFMA16 per chunk.
// ---------------------------------------------------------------------------
__global__ __launch_bounds__(512, 4) void qkv_fused(
    const float* __restrict__ x, const u16* __restrict__ Wb,
    const float* __restrict__ bq, const float* __restrict__ bk,
    const float* __restrict__ bv,
    u16* __restrict__ qo, u16* __restrict__ kT, u16* __restrict__ vT)
{
    // pool 20 KB: main loop A bufs [0..1023],[1024..2047] u16
    // epilogue ph1: Eq[32][136] (4352 u16); ph2: Ek[128][40]+Ev[128][40] (10240)
    __shared__ __align__(16) u16 smem[10240];

    const int m0 = blockIdx.x * 32;
    const int tid = threadIdx.x, lane = tid & 63, w = tid >> 6;
    const int quad = lane >> 4, l16 = lane & 15;
    const int wn = w * 3;            // first n16 of this wave (3 x 16 = 48 cols)

    // A staging: 256 threads, thread -> (row arow, 4-float col seg ac4)
    const bool aload = tid < 256;
    const int arow = tid >> 3, ac4 = tid & 7;          // valid when aload
    const float* xp = x + (size_t)(m0 + arow) * 1024 + ac4 * 4;
    const int adst = (arow >> 4) * 512 + ((ac4 >> 1) * 16 + (arow & 15)) * 8 + (ac4 & 1) * 4;

    // B: wave w reads frags wn..wn+2 of each chunk straight to VGPRs
    const u16* wb0 = Wb + wn * 512 + lane * 8;         // chunk stride 12288 u16

    f32x4 acc[2][3] = {};

    // ---- prologue: x(0..3); B(0),B(1); stage A(0) into buf0 ----
    float4 xq[4];
    bf16x8 breg[3][3];
    if (aload) {
        xq[0] = *(const float4*)(xp);
        xq[1] = *(const float4*)(xp + 32);
        xq[2] = *(const float4*)(xp + 64);
        xq[3] = *(const float4*)(xp + 96);
    }
    #pragma unroll
    for (int j = 0; j < 3; ++j) breg[0][j] = ld_frag(wb0 + j * 512);
    #pragma unroll
    for (int j = 0; j < 3; ++j) breg[1][j] = ld_frag(wb0 + 12288 + j * 512);
    __builtin_amdgcn_sched_barrier(0);   // pin prologue issues
    if (aload) *(u16x4*)&smem[adst] = pack4(xq[0]);

    #pragma unroll
    for (int c = 0; c < 32; ++c) {
        wg_barrier();                // A buf[c&1] ready; vm prefetches live on

        // ---- pinned issue cluster: x(c+4) and B(c+2) leave HERE ----
        if (c < 28 && aload)
            xq[c & 3] = *(const float4*)(xp + (c + 4) * 32);
        if (c < 30) {
            #pragma unroll
            for (int j = 0; j < 3; ++j)
                breg[(c + 2) % 3][j] = ld_frag(wb0 + (size_t)(c + 2) * 12288 + j * 512);
        }
        __builtin_amdgcn_sched_barrier(0);   // loads may NOT sink below

        // write A(c+1) into buf[(c+1)&1] (x(c+1) issued at c-3: vmcnt counted)
        if (c < 31 && aload)
            *(u16x4*)&smem[((c + 1) & 1) * 1024 + adst] = pack4(xq[(c + 1) & 3]);

        // compute chunk c (identity ds_read_b128, conflict-free)
        const u16* Ac = &smem[(c & 1) * 1024];
        bf16x8 af0 = ld_frag(&Ac[lane * 8]);
        bf16x8 af1 = ld_frag(&Ac[512 + lane * 8]);
        #pragma unroll
        for (int j = 0; j < 3; ++j) {
            acc[0][j] = MFMA16(af0, breg[c % 3][j], acc[0][j]);
            acc[1][j] = MFMA16(af1, breg[c % 3][j], acc[1][j]);
        }
    }

    // -------- epilogue, phase 1: q (n16g 0..7), Eq[32][136] --------
    __syncthreads();
    u16* Eq = smem;
    #pragma unroll
    for (int j = 0; j < 3; ++j) {
        int n16g = wn + j;
        if (n16g < 8) {
            int col = n16g * 16 + l16;
            float bb = bq[col];
            #pragma unroll
            for (int mi = 0; mi < 2; ++mi)
                #pragma unroll
                for (int r = 0; r < 4; ++r)
                    Eq[(mi * 16 + quad * 4 + r) * 136 + col] =
                        f2bf(acc[mi][j][r] + bb);
        }
    }
    __syncthreads();
    {
        int row = tid >> 4, d8 = (tid & 15) * 8;       // 32 rows x 128 d
        *(u16x8*)(qo + (size_t)(m0 + row) * 128 + d8) = *(u16x8*)&Eq[row * 136 + d8];
    }

    // -------- epilogue, phase 2: k,v transposed, Ek/Ev[128][40] --------
    __syncthreads();
    u16* Ek = smem;
    u16* Ev = smem + 5120;
    #pragma unroll
    for (int j = 0; j < 3; ++j) {
        int n16g = wn + j;
        if (n16g >= 8) {
            int col = (n16g & 7) * 16 + l16;           // d
            const float* bias = (n16g < 16) ? bk : bv;
            u16* E = (n16g < 16) ? Ek : Ev;
            float bb = bias[col];
            #pragma unroll
            for (int mi = 0; mi < 2; ++mi) {
                u16x4 v4 = { f2bf(acc[mi][j][0] + bb), f2bf(acc[mi][j][1] + bb),
                             f2bf(acc[mi][j][2] + bb), f2bf(acc[mi][j][3] + bb) };
                *(u16x4*)&E[col * 40 + mi * 16 + quad * 4] = v4;
            }
        }
    }
    __syncthreads();
    {
        int d = tid >> 2, t8 = (tid & 3) * 8;          // 128 d x 32 t
        *(u16x8*)(kT + (size_t)d * 16384 + m0 + t8) = *(u16x8*)&Ek[d * 40 + t8];
        *(u16x8*)(vT + (size_t)d * 16384 + m0 + t8) = *(u16x8*)&Ev[d * 40 + t8];
    }
}

// ---------------------------------------------------------------------------
// kt_v: partial T[e][d] = sum_t vT[e][t]*kT[d][t] over a 128-t chunk.
// grid (32,4), 512 threads / 8 waves (wave 64e x 32d).
// ---------------------------------------------------------------------------
__global__ __launch_bounds__(512) void kt_v(
    const u16* __restrict__ kT, const u16* __restrict__ vT,
    float* __restrict__ part)
{
    __shared__ __align__(16) u16 vL[128 * 136];
    __shared__ __align__(16) u16 kL[128 * 136];

    const int c = blockIdx.x, b = blockIdx.y;
    const size_t g0 = (size_t)b * 4096 + c * 128;
    const int tid = threadIdx.x, lane = tid & 63, w = tid >> 6;
    const int quad = lane >> 4, l16 = lane & 15;
    const int we = (w >> 2) * 64, wd = (w & 3) * 32;

    #pragma unroll
    for (int i = 0; i < 4; ++i) {
        int idx = tid + i * 512;
        int e = idx >> 4, t8 = (idx & 15) * 8;
        *(u16x8*)&vL[e * 136 + t8] = *(const u16x8*)(vT + (size_t)e * 16384 + g0 + t8);
        *(u16x8*)&kL[e * 136 + t8] = *(const u16x8*)(kT + (size_t)e * 16384 + g0 + t8);
    }
    __syncthreads();

    f32x4 acc[4][2] = {};
    #pragma unroll
    for (int ks = 0; ks < 4; ++ks) {
        bf16x8 af[4], bfr[2];
        #pragma unroll
        for (int mi = 0; mi < 4; ++mi)
            af[mi] = ld_frag(&vL[(we + mi * 16 + l16) * 136 + ks * 32 + quad * 8]);
        #pragma unroll
        for (int ni = 0; ni < 2; ++ni)
            bfr[ni] = ld_frag(&kL[(wd + ni * 16 + l16) * 136 + ks * 32 + quad * 8]);
        #pragma unroll
        for (int mi = 0; mi < 4; ++mi)
            #pragma unroll
            for (int ni = 0; ni < 2; ++ni)
                acc[mi][ni] = MFMA16(af[mi], bfr[ni], acc[mi][ni]);
    }

    float* dst = part + (size_t)(b * 32 + c) * 16384;
    #pragma unroll
    for (int mi = 0; mi < 4; ++mi)
        #pragma unroll
        for (int ni = 0; ni < 2; ++ni)
            #pragma unroll
            for (int r = 0; r < 4; ++r)
                dst[(we + mi * 16 + quad * 4 + r) * 128 + (wd + ni * 16 + l16)] =
                    acc[mi][ni][r];
}

// ---------------------------------------------------------------------------
// reduceT: 32 fp32 partials -> T bf16 [4][128][128], scale folded in.
// ---------------------------------------------------------------------------
__global__ __launch_bounds__(256) void reduceT(
    const float* __restrict__ part, u16* __restrict__ T)
{
    int gid = blockIdx.x * 256 + threadIdx.x;   // 0..65535
    int b = gid >> 14, idx = gid & 16383;
    const float* p = part + (size_t)b * 32 * 16384 + idx;
    float s = 0.f;
    #pragma unroll
    for (int c = 0; c < 32; ++c) s += p[(size_t)c * 16384];
    T[gid] = f2bf(s * 0.088388347648318447f);   // 128^-0.5
}

// ---------------------------------------------------------------------------
// out_gemm: outT-form — C[e][s], A=T[e][d], B=q[s][d] (both d-contig).
// C/D layout gives out[s][e] as contiguous f32x4 -> full-line stores.
// grid 512 (32-s tiles, 2 blocks/CU), 4 waves: wave 64e x 16s.
// ---------------------------------------------------------------------------
__global__ __launch_bounds__(256) void out_gemm(
    const u16* __restrict__ qo, const u16* __restrict__ T,
    float* __restrict__ out)
{
    __shared__ __align__(16) u16 tL[128 * 136];
    __shared__ __align__(16) u16 qL[32 * 136];

    const int s0 = blockIdx.x * 32;
    const int b  = s0 >> 12;
    const int tid = threadIdx.x, lane = tid & 63, w = tid >> 6;
    const int quad = lane >> 4, l16 = lane & 15;
    const int we = (w >> 1) * 64, wsx = (w & 1) * 16;

    #pragma unroll
    for (int i = 0; i < 8; ++i) {
        int idx = tid + i * 256;
        int e = idx >> 4, d8 = (idx & 15) * 8;
        *(u16x8*)&tL[e * 136 + d8] = *(const u16x8*)(T + (size_t)b * 16384 + e * 128 + d8);
    }
    #pragma unroll
    for (int i = 0; i < 2; ++i) {
        int idx = tid + i * 256;
        int sr = idx >> 4, d8 = (idx & 15) * 8;
        *(u16x8*)&qL[sr * 136 + d8] = *(const u16x8*)(qo + (size_t)(s0 + sr) * 128 + d8);
    }
    __syncthreads();

    f32x4 acc[4] = {};
    #pragma unroll
    for (int ks = 0; ks < 4; ++ks) {
        bf16x8 bfr = ld_frag(&qL[(wsx + l16) * 136 + ks * 32 + quad * 8]);
        #pragma unroll
        for (int mi = 0; mi < 4; ++mi) {
            bf16x8 af = ld_frag(&tL[(we + mi * 16 + l16) * 136 + ks * 32 + quad * 8]);
            acc[mi] = MFMA16(af, bfr, acc[mi]);
        }
    }

    #pragma unroll
    for (int mi = 0; mi < 4; ++mi) {
        int s = s0 + wsx + l16;
        int e0 = we + mi * 16 + quad * 4;
        *(f32x4*)(out + (size_t)s * 128 + e0) = acc[mi];
    }
}

// ---------------------------------------------------------------------------
extern "C" void kernel_launch(void* const* d_in, const int* in_sizes, int n_in,
                              void* d_out, int out_size, void* d_ws, size_t ws_size,
                              hipStream_t stream)
{
    const float* x  = (const float*)d_in[0];
    const float* Wq = (const float*)d_in[1];
    const float* bq = (const float*)d_in[2];
    const float* Wk = (const float*)d_in[3];
    const float* bk = (const float*)d_in[4];
    const float* Wv = (const float*)d_in[5];
    const float* bv = (const float*)d_in[6];
    float* out = (float*)d_out;

    char* ws = (char*)d_ws;
    u16*   qo   = (u16*)(ws);                          //  4 MB, [s][d]
    u16*   kT   = (u16*)(ws + ((size_t)4 << 20));      //  4 MB, [d][t]
    u16*   vT   = (u16*)(ws + ((size_t)8 << 20));      //  4 MB, [e][t]
    // Wb (768 KB) aliases part (8 MB): Wb dead before kt_v writes part.
    u16*   Wb   = (u16*)(ws + ((size_t)12 << 20));
    float* part = (float*)(ws + ((size_t)12 << 20));
    u16*   T    = (u16*)(ws + ((size_t)20 << 20));     // 128 KB

    hipLaunchKernelGGL(wcvt, dim3(192), dim3(256), 0, stream, Wq, Wk, Wv, Wb);
    hipLaunchKernelGGL(qkv_fused, dim3(512), dim3(512), 0, stream,
                       x, Wb, bq, bk, bv, qo, kT, vT);
    hipLaunchKernelGGL(kt_v, dim3(32, 4), dim3(512), 0, stream, kT, vT, part);
    hipLaunchKernelGGL(reduceT, dim3(256), dim3(256), 0, stream, part, T);
    hipLaunchKernelGGL(out_gemm, dim3(512), dim3(256), 0, stream, qo, T, out);
}

// Round 5
// 134.566 us; speedup vs baseline: 1.0765x; 1.0765x over previous
//
#include <hip/hip_runtime.h>

typedef __bf16 bf16x8 __attribute__((ext_vector_type(8)));
typedef float f32x4 __attribute__((ext_vector_type(4)));
typedef unsigned short u16;
typedef unsigned short u16x4 __attribute__((ext_vector_type(4)));
typedef unsigned short u16x8 __attribute__((ext_vector_type(8)));

#define MFMA16(a, b, c) __builtin_amdgcn_mfma_f32_16x16x32_bf16(a, b, c, 0, 0, 0)

__device__ __forceinline__ u16 f2bf(float f) {
    unsigned u = __builtin_bit_cast(unsigned, f);
    u += 0x7fffu + ((u >> 16) & 1u);   // RNE
    return (u16)(u >> 16);
}

__device__ __forceinline__ bf16x8 ld_frag(const u16* p) {
    u16x8 v = *(const u16x8*)p;
    return __builtin_bit_cast(bf16x8, v);
}

__device__ __forceinline__ u16x8 pack8(float4 a, float4 b) {
    u16x8 o = { f2bf(a.x), f2bf(a.y), f2bf(a.z), f2bf(a.w),
                f2bf(b.x), f2bf(b.y), f2bf(b.z), f2bf(b.w) };
    return o;
}

// ---------------------------------------------------------------------------
// wcvt: Wq|Wk|Wv fp32 -> Wb bf16, N-fused B-fragment order, BK=32 chunks.
// Wb u16 off = ((cc*24 + n16)*64 + lane)*8 ;  lane=(quad,l16), cc in 0..31
// element = Wcat[n16*16 + l16][cc*32 + quad*8 + j],  Wcat=[Wq;Wk;Wv]
// ---------------------------------------------------------------------------
__global__ __launch_bounds__(256) void wcvt(
    const float* __restrict__ Wq, const float* __restrict__ Wk,
    const float* __restrict__ Wv, u16* __restrict__ Wb)
{
    int g = blockIdx.x * 256 + threadIdx.x;   // 49152
    int lane = g & 63, l16 = g & 15, quad = (g >> 4) & 3;
    int n16 = (g >> 6) % 24;
    int cc  = (g >> 6) / 24;
    int nrow = n16 * 16 + l16;                // 0..383
    int nt = nrow >> 7, r = nrow & 127;
    int col = cc * 32 + quad * 8;
    const float* W = (nt == 0 ? Wq : nt == 1 ? Wk : Wv) + (size_t)r * 1024 + col;
    float4 a = *(const float4*)(W);
    float4 b = *(const float4*)(W + 4);
    (void)lane;
    *(u16x8*)(Wb + (size_t)g * 8) = pack8(a, b);
}

// ---------------------------------------------------------------------------
// qkv_fused v5: q|k|v = x @ W^T + b.  grid 512 (M-tile 32), 512 thr / 8 waves.
// N=384 fully fused (x read ONCE). BK=32.
// v4 post-mortem: VGPR stayed 52 — sched_barrier did NOT pin the prefetch;
// the per-chunk barrier structure is unfixable at source level. v5 removes
// the disease: per-chunk workgroup rendezvous.
//   - Stage ALL of A up front: 32x1024 fp32 -> bf16 fragment-order LDS
//     (64 KB), each lane loads its own fragment (2x float4, 128B-contiguous
//     row segments) and writes ONE ds_write_b128 at lane*16 (conflict-free).
//     One __syncthreads total.
//   - Main loop: NO barriers. 32 chunks x {3 B-frag global loads (L2-hot),
//     2 ds_read_b128, 6 MFMA}. Waves slip freely; 16 waves/CU of TLP hide
//     load latency even if the compiler serializes each wave's chain.
// Wave tile 32m x 48n: 2 A-frags, 3 B-frags, 6 MFMA16 per chunk.
// Epilogue unchanged (verified): q natural, then kT/vT [d][t].
// ---------------------------------------------------------------------------
__global__ __launch_bounds__(512, 4) void qkv_fused(
    const float* __restrict__ x, const u16* __restrict__ Wb,
    const float* __restrict__ bq, const float* __restrict__ bk,
    const float* __restrict__ bv,
    u16* __restrict__ qo, u16* __restrict__ kT, u16* __restrict__ vT)
{
    // 64 KB: A frag-order [c 0..31][m16 0..1][lane 0..63][8] u16.
    // Epilogue aliases the pool (<=10240 u16) after a barrier.
    __shared__ __align__(16) u16 smem[32768];

    const int m0 = blockIdx.x * 32;
    const int tid = threadIdx.x, lane = tid & 63, w = tid >> 6;
    const int quad = lane >> 4, l16 = lane & 15;
    const int wn = w * 3;            // first n16 of this wave (3 x 16 = 48 cols)

    // ---- stage phase: frag-block idx = w*8 + k -> c = idx>>1, m16 = idx&1.
    // lane covers row m16*16+l16, cols c*32 + quad*8 .. +7 (8 floats).
    {
        float4 xa[8], xb[8];
        #pragma unroll
        for (int k = 0; k < 8; ++k) {
            int idx = w * 8 + k, c = idx >> 1, m16 = idx & 1;
            const float* p = x + (size_t)(m0 + m16 * 16 + l16) * 1024 + c * 32 + quad * 8;
            xa[k] = *(const float4*)(p);
            xb[k] = *(const float4*)(p + 4);
        }
        #pragma unroll
        for (int k = 0; k < 8; ++k) {
            int idx = w * 8 + k;
            *(u16x8*)&smem[idx * 512 + lane * 8] = pack8(xa[k], xb[k]);
        }
    }

    // B: wave w reads frags wn..wn+2 of each chunk straight to VGPRs
    const u16* wb0 = Wb + wn * 512 + lane * 8;         // chunk stride 12288 u16

    f32x4 acc[2][3] = {};
    __syncthreads();                 // A fully staged; ONLY loop barrier

    // ---- main loop: barrier-free; TLP (16 waves/CU) hides latency ----
    #pragma unroll
    for (int c = 0; c < 32; ++c) {
        bf16x8 bfr[3];
        #pragma unroll
        for (int j = 0; j < 3; ++j)
            bfr[j] = ld_frag(wb0 + (size_t)c * 12288 + j * 512);
        bf16x8 af0 = ld_frag(&smem[(c * 2 + 0) * 512 + lane * 8]);
        bf16x8 af1 = ld_frag(&smem[(c * 2 + 1) * 512 + lane * 8]);
        #pragma unroll
        for (int j = 0; j < 3; ++j) {
            acc[0][j] = MFMA16(af0, bfr[j], acc[0][j]);
            acc[1][j] = MFMA16(af1, bfr[j], acc[1][j]);
        }
    }

    // -------- epilogue, phase 1: q (n16g 0..7), Eq[32][136] --------
    __syncthreads();
    u16* Eq = smem;
    #pragma unroll
    for (int j = 0; j < 3; ++j) {
        int n16g = wn + j;
        if (n16g < 8) {
            int col = n16g * 16 + l16;
            float bb = bq[col];
            #pragma unroll
            for (int mi = 0; mi < 2; ++mi)
                #pragma unroll
                for (int r = 0; r < 4; ++r)
                    Eq[(mi * 16 + quad * 4 + r) * 136 + col] =
                        f2bf(acc[mi][j][r] + bb);
        }
    }
    __syncthreads();
    {
        int row = tid >> 4, d8 = (tid & 15) * 8;       // 32 rows x 128 d
        *(u16x8*)(qo + (size_t)(m0 + row) * 128 + d8) = *(u16x8*)&Eq[row * 136 + d8];
    }

    // -------- epilogue, phase 2: k,v transposed, Ek/Ev[128][40] --------
    __syncthreads();
    u16* Ek = smem;
    u16* Ev = smem + 5120;
    #pragma unroll
    for (int j = 0; j < 3; ++j) {
        int n16g = wn + j;
        if (n16g >= 8) {
            int col = (n16g & 7) * 16 + l16;           // d
            const float* bias = (n16g < 16) ? bk : bv;
            u16* E = (n16g < 16) ? Ek : Ev;
            float bb = bias[col];
            #pragma unroll
            for (int mi = 0; mi < 2; ++mi) {
                u16x4 v4 = { f2bf(acc[mi][j][0] + bb), f2bf(acc[mi][j][1] + bb),
                             f2bf(acc[mi][j][2] + bb), f2bf(acc[mi][j][3] + bb) };
                *(u16x4*)&E[col * 40 + mi * 16 + quad * 4] = v4;
            }
        }
    }
    __syncthreads();
    {
        int d = tid >> 2, t8 = (tid & 3) * 8;          // 128 d x 32 t
        *(u16x8*)(kT + (size_t)d * 16384 + m0 + t8) = *(u16x8*)&Ek[d * 40 + t8];
        *(u16x8*)(vT + (size_t)d * 16384 + m0 + t8) = *(u16x8*)&Ev[d * 40 + t8];
    }
}

// ---------------------------------------------------------------------------
// kt_v: partial T[e][d] = sum_t vT[e][t]*kT[d][t] over a 128-t chunk.
// grid (32,4), 512 threads / 8 waves (wave 64e x 32d).
// ---------------------------------------------------------------------------
__global__ __launch_bounds__(512) void kt_v(
    const u16* __restrict__ kT, const u16* __restrict__ vT,
    float* __restrict__ part)
{
    __shared__ __align__(16) u16 vL[128 * 136];
    __shared__ __align__(16) u16 kL[128 * 136];

    const int c = blockIdx.x, b = blockIdx.y;
    const size_t g0 = (size_t)b * 4096 + c * 128;
    const int tid = threadIdx.x, lane = tid & 63, w = tid >> 6;
    const int quad = lane >> 4, l16 = lane & 15;
    const int we = (w >> 2) * 64, wd = (w & 3) * 32;

    #pragma unroll
    for (int i = 0; i < 4; ++i) {
        int idx = tid + i * 512;
        int e = idx >> 4, t8 = (idx & 15) * 8;
        *(u16x8*)&vL[e * 136 + t8] = *(const u16x8*)(vT + (size_t)e * 16384 + g0 + t8);
        *(u16x8*)&kL[e * 136 + t8] = *(const u16x8*)(kT + (size_t)e * 16384 + g0 + t8);
    }
    __syncthreads();

    f32x4 acc[4][2] = {};
    #pragma unroll
    for (int ks = 0; ks < 4; ++ks) {
        bf16x8 af[4], bfr[2];
        #pragma unroll
        for (int mi = 0; mi < 4; ++mi)
            af[mi] = ld_frag(&vL[(we + mi * 16 + l16) * 136 + ks * 32 + quad * 8]);
        #pragma unroll
        for (int ni = 0; ni < 2; ++ni)
            bfr[ni] = ld_frag(&kL[(wd + ni * 16 + l16) * 136 + ks * 32 + quad * 8]);
        #pragma unroll
        for (int mi = 0; mi < 4; ++mi)
            #pragma unroll
            for (int ni = 0; ni < 2; ++ni)
                acc[mi][ni] = MFMA16(af[mi], bfr[ni], acc[mi][ni]);
    }

    float* dst = part + (size_t)(b * 32 + c) * 16384;
    #pragma unroll
    for (int mi = 0; mi < 4; ++mi)
        #pragma unroll
        for (int ni = 0; ni < 2; ++ni)
            #pragma unroll
            for (int r = 0; r < 4; ++r)
                dst[(we + mi * 16 + quad * 4 + r) * 128 + (wd + ni * 16 + l16)] =
                    acc[mi][ni][r];
}

// ---------------------------------------------------------------------------
// reduceT: 32 fp32 partials -> T bf16 [4][128][128], scale folded in.
// ---------------------------------------------------------------------------
__global__ __launch_bounds__(256) void reduceT(
    const float* __restrict__ part, u16* __restrict__ T)
{
    int gid = blockIdx.x * 256 + threadIdx.x;   // 0..65535
    int b = gid >> 14, idx = gid & 16383;
    const float* p = part + (size_t)b * 32 * 16384 + idx;
    float s = 0.f;
    #pragma unroll
    for (int c = 0; c < 32; ++c) s += p[(size_t)c * 16384];
    T[gid] = f2bf(s * 0.088388347648318447f);   // 128^-0.5
}

// ---------------------------------------------------------------------------
// out_gemm: outT-form — C[e][s], A=T[e][d], B=q[s][d] (both d-contig).
// C/D layout gives out[s][e] as contiguous f32x4 -> full-line stores.
// grid 512 (32-s tiles, 2 blocks/CU), 4 waves: wave 64e x 16s.
// ---------------------------------------------------------------------------
__global__ __launch_bounds__(256) void out_gemm(
    const u16* __restrict__ qo, const u16* __restrict__ T,
    float* __restrict__ out)
{
    __shared__ __align__(16) u16 tL[128 * 136];
    __shared__ __align__(16) u16 qL[32 * 136];

    const int s0 = blockIdx.x * 32;
    const int b  = s0 >> 12;
    const int tid = threadIdx.x, lane = tid & 63, w = tid >> 6;
    const int quad = lane >> 4, l16 = lane & 15;
    const int we = (w >> 1) * 64, wsx = (w & 1) * 16;

    #pragma unroll
    for (int i = 0; i < 8; ++i) {
        int idx = tid + i * 256;
        int e = idx >> 4, d8 = (idx & 15) * 8;
        *(u16x8*)&tL[e * 136 + d8] = *(const u16x8*)(T + (size_t)b * 16384 + e * 128 + d8);
    }
    #pragma unroll
    for (int i = 0; i < 2; ++i) {
        int idx = tid + i * 256;
        int sr = idx >> 4, d8 = (idx & 15) * 8;
        *(u16x8*)&qL[sr * 136 + d8] = *(const u16x8*)(qo + (size_t)(s0 + sr) * 128 + d8);
    }
    __syncthreads();

    f32x4 acc[4] = {};
    #pragma unroll
    for (int ks = 0; ks < 4; ++ks) {
        bf16x8 bfr = ld_frag(&qL[(wsx + l16) * 136 + ks * 32 + quad * 8]);
        #pragma unroll
        for (int mi = 0; mi < 4; ++mi) {
            bf16x8 af = ld_frag(&tL[(we + mi * 16 + l16) * 136 + ks * 32 + quad * 8]);
            acc[mi] = MFMA16(af, bfr, acc[mi]);
        }
    }

    #pragma unroll
    for (int mi = 0; mi < 4; ++mi) {
        int s = s0 + wsx + l16;
        int e0 = we + mi * 16 + quad * 4;
        *(f32x4*)(out + (size_t)s * 128 + e0) = acc[mi];
    }
}

// ---------------------------------------------------------------------------
extern "C" void kernel_launch(void* const* d_in, const int* in_sizes, int n_in,
                              void* d_out, int out_size, void* d_ws, size_t ws_size,
                              hipStream_t stream)
{
    const float* x  = (const float*)d_in[0];
    const float* Wq = (const float*)d_in[1];
    const float* bq = (const float*)d_in[2];
    const float* Wk = (const float*)d_in[3];
    const float* bk = (const float*)d_in[4];
    const float* Wv = (const float*)d_in[5];
    const float* bv = (const float*)d_in[6];
    float* out = (float*)d_out;

    char* ws = (char*)d_ws;
    u16*   qo   = (u16*)(ws);                          //  4 MB, [s][d]
    u16*   kT   = (u16*)(ws + ((size_t)4 << 20));      //  4 MB, [d][t]
    u16*   vT   = (u16*)(ws + ((size_t)8 << 20));      //  4 MB, [e][t]
    // Wb (768 KB) aliases part (8 MB): Wb dead before kt_v writes part.
    u16*   Wb   = (u16*)(ws + ((size_t)12 << 20));
    float* part = (float*)(ws + ((size_t)12 << 20));
    u16*   T    = (u16*)(ws + ((size_t)20 << 20));     // 128 KB

    hipLaunchKernelGGL(wcvt, dim3(192), dim3(256), 0, stream, Wq, Wk, Wv, Wb);
    hipLaunchKernelGGL(qkv_fused, dim3(512), dim3(512), 0, stream,
                       x, Wb, bq, bk, bv, qo, kT, vT);
    hipLaunchKernelGGL(kt_v, dim3(32, 4), dim3(512), 0, stream, kT, vT, part);
    hipLaunchKernelGGL(reduceT, dim3(256), dim3(256), 0, stream, part, T);
    hipLaunchKernelGGL(out_gemm, dim3(512), dim3(256), 0, stream, qo, T, out);
}